// Round 3
// baseline (198.524 us; speedup 1.0000x reference)
//
#include <hip/hip_runtime.h>
#include <hip/hip_bf16.h>

#define H 768
#define NH 12
#define DH 64
#define LL 8
#define NTOK 16384   // B*S = 8*2048
#define NREL 100
#define NRELP 128    // padded to BM

typedef __attribute__((ext_vector_type(8))) short short8;
typedef __attribute__((ext_vector_type(4))) float f32x4;

__device__ __forceinline__ float bf2f(ushort u) {
  union { unsigned int i; float f; } v; v.i = ((unsigned int)u) << 16; return v.f;
}
__device__ __forceinline__ ushort f2bf(float f) {
  union { float f; unsigned int i; } v; v.f = f;
  unsigned int x = v.i;
  return (ushort)((x + 0x7fffu + ((x >> 16) & 1u)) >> 16);  // RNE
}

// ---------------------------------------------------------------- cvt f32->bf16
__global__ __launch_bounds__(256) void cvt_kernel(const float* __restrict__ src,
                                                  ushort* __restrict__ dst) {
  int i = (blockIdx.x * 256 + threadIdx.x) * 4;
  float4 v = *(const float4*)(src + i);
  ushort4 o; o.x = f2bf(v.x); o.y = f2bf(v.y); o.z = f2bf(v.z); o.w = f2bf(v.w);
  *(ushort4*)(dst + i) = o;
}

// -------------------------------- rel_table [100][768] f32 -> [128][768] bf16
__global__ __launch_bounds__(256) void rel_cvt_kernel(const float* __restrict__ src,
                                                      ushort* __restrict__ dst) {
  int i = blockIdx.x * 256 + threadIdx.x;      // 0 .. 128*768-1
  int row = i / H;
  dst[i] = (row < NREL) ? f2bf(src[i]) : (ushort)0;
}

// ------------------------------------------------- transpose [H][H] f32 -> bf16
__global__ __launch_bounds__(256) void transpose_bf16_kernel(const float* __restrict__ src,
                                                             ushort* __restrict__ dst) {
  __shared__ float tile[32][33];
  int bx = blockIdx.x * 32, by = blockIdx.y * 32;
  int tx = threadIdx.x & 31, ty = threadIdx.x >> 5;  // ty 0..7
  #pragma unroll
  for (int i = 0; i < 32; i += 8)
    tile[ty + i][tx] = src[(size_t)(by + ty + i) * H + bx + tx];
  __syncthreads();
  #pragma unroll
  for (int i = 0; i < 32; i += 8)
    dst[(size_t)(bx + ty + i) * H + by + tx] = f2bf(tile[tx][ty + i]);
}

// ------------------------------------------------------------- bf16 MFMA GEMM
// C[M][N] = A[M][K] @ Bt[N][K]^T + bias, all bf16 in / bf16 out, fp32 accum.
__device__ __forceinline__ void gload_lds16(const void* g, void* l) {
  __builtin_amdgcn_global_load_lds(
      (const __attribute__((address_space(1))) unsigned int*)g,
      (__attribute__((address_space(3))) unsigned int*)l, 16, 0, 0);
}

#define BM 128
#define BN 128
#define BK 32

__global__ __launch_bounds__(256, 2) void gemm_bt_kernel(
    const ushort* __restrict__ A,    // [M][K]
    const ushort* __restrict__ Bt,   // [N][K]
    const float* __restrict__ bias,  // [N]
    ushort* __restrict__ C,          // [M][N]
    int M, int N, int K) {
  __shared__ ushort As[BM * BK];   // 8 KB, row-major [BM][BK]
  __shared__ ushort Bs[BN * BK];   // 8 KB
  const int tid = threadIdx.x;
  const int row0 = blockIdx.y * BM;
  const int col0 = blockIdx.x * BN;
  const int wave = tid >> 6;
  const int lane = tid & 63;
  const int wr = wave >> 1, wc = wave & 1;     // 2x2 waves, 64x64 each
  const int lr = lane & 15, lk = lane >> 4;    // frag row/col & k-group
  f32x4 acc[4][4];
  #pragma unroll
  for (int m = 0; m < 4; ++m)
    #pragma unroll
    for (int n = 0; n < 4; ++n) acc[m][n] = (f32x4)(0.f);

  for (int k0 = 0; k0 < K; k0 += BK) {
    #pragma unroll
    for (int i = 0; i < 2; ++i) {
      int c = tid + i * 256;        // 16B chunk id, 512 chunks per 8KB tile
      int r = c >> 2, q = c & 3;    // tile row, quarter-row (8 bf16)
      gload_lds16(A  + (size_t)(row0 + r) * K + k0 + q * 8, (char*)As + c * 16);
      gload_lds16(Bt + (size_t)(col0 + r) * K + k0 + q * 8, (char*)Bs + c * 16);
    }
    __syncthreads();
    short8 af[4], bfr[4];
    #pragma unroll
    for (int m = 0; m < 4; ++m)
      af[m] = *(const short8*)(As + (wr * 64 + m * 16 + lr) * BK + lk * 8);
    #pragma unroll
    for (int n = 0; n < 4; ++n)
      bfr[n] = *(const short8*)(Bs + (wc * 64 + n * 16 + lr) * BK + lk * 8);
    #pragma unroll
    for (int m = 0; m < 4; ++m)
      #pragma unroll
      for (int n = 0; n < 4; ++n)
        acc[m][n] = __builtin_amdgcn_mfma_f32_16x16x32_bf16(af[m], bfr[n], acc[m][n], 0, 0, 0);
    __syncthreads();
  }
  // epilogue: C/D layout col = lane&15, row = (lane>>4)*4 + j  [verified m89/m91]
  #pragma unroll
  for (int m = 0; m < 4; ++m) {
    #pragma unroll
    for (int n = 0; n < 4; ++n) {
      int col = col0 + wc * 64 + n * 16 + lr;
      float b = bias[col];
      #pragma unroll
      for (int j = 0; j < 4; ++j) {
        int row = row0 + wr * 64 + m * 16 + lk * 4 + j;
        C[(size_t)row * N + col] = f2bf(acc[m][n][j] + b);
      }
    }
  }
}

// ---------------------------------------------- MFMA-based GAT attention (v2)
// Block = 256 thr (4 waves), handles 64 tokens x 1 head. Each wave: 16 tokens.
// S = Q_tile @ Ktab_head^T via MFMA (K/V tables are L2-resident: no staging).
// Softmax: 4 lanes per token. PV: per-leaf VALU accumulation (exact dup-rid).
#define SP 132   // S strip padded cols (f32)
__global__ __launch_bounds__(256) void attn2_kernel(
    const ushort* __restrict__ Q,     // [NTOK][H] bf16
    const ushort* __restrict__ Ktab,  // [NRELP][H] bf16
    const ushort* __restrict__ Vtab,  // [NRELP][H] bf16
    const int* __restrict__ graph,    // [NTOK][LL]
    const int* __restrict__ relid,    // [NTOK][LL]
    ushort* __restrict__ Ctx) {       // [NTOK][H] bf16
  __shared__ ushort Qs[64 * 64];          // 8 KB, linear (gload_lds dest)
  __shared__ float  Ss[4][16 * SP];       // 33.8 KB, wave-private strips
  const int tid  = threadIdx.x;
  const int wave = tid >> 6, lane = tid & 63;
  const int lr = lane & 15, lk = lane >> 4;
  const int tok0 = blockIdx.x * 64;
  const int head = blockIdx.y;

  // ---- stage Q tile [64 tok][64 dims] -> LDS (2 x 16B chunks per thread)
  #pragma unroll
  for (int i = 0; i < 2; ++i) {
    int c = tid + i * 256;               // chunk: row = c>>3, seg = c&7
    gload_lds16(Q + (size_t)(tok0 + (c >> 3)) * H + head * DH + (c & 7) * 8,
                (char*)Qs + c * 16);
  }
  __syncthreads();

  // ---- S = Q(16 rows of this wave) @ Ktab_head^T : 8 n-tiles x 2 k-steps
  short8 af0 = *(const short8*)(Qs + (wave * 16 + lr) * 64 + 0 + lk * 8);
  short8 af1 = *(const short8*)(Qs + (wave * 16 + lr) * 64 + 32 + lk * 8);
  f32x4 acc[8];
  #pragma unroll
  for (int nt = 0; nt < 8; ++nt) acc[nt] = (f32x4)(0.f);
  #pragma unroll
  for (int nt = 0; nt < 8; ++nt) {
    const ushort* kb = Ktab + (size_t)(nt * 16 + lr) * H + head * DH + lk * 8;
    short8 b0 = *(const short8*)(kb);
    short8 b1 = *(const short8*)(kb + 32);
    acc[nt] = __builtin_amdgcn_mfma_f32_16x16x32_bf16(af0, b0, acc[nt], 0, 0, 0);
    acc[nt] = __builtin_amdgcn_mfma_f32_16x16x32_bf16(af1, b1, acc[nt], 0, 0, 0);
  }
  // ---- spill S strip (C/D: col = lr, row = lk*4+j) — wave-private, no barrier
  float* S = Ss[wave];
  #pragma unroll
  for (int nt = 0; nt < 8; ++nt)
    #pragma unroll
    for (int j = 0; j < 4; ++j)
      S[(lk * 4 + j) * SP + nt * 16 + lr] = acc[nt][j];

  // ---- softmax: 4 lanes per token; lane sub=lane>>4 owns leaves {2sub,2sub+1}
  const int tk = lane & 15, sub = lane >> 4;
  const int t = tok0 + wave * 16 + tk;
  int2 g2 = *(const int2*)(graph + (size_t)t * LL + sub * 2);
  int2 r2 = *(const int2*)(relid + (size_t)t * LL + sub * 2);
  int r0 = r2.x < 0 ? 0 : r2.x;
  int r1 = r2.y < 0 ? 0 : r2.y;
  float s0 = (g2.x != -1) ? S[tk * SP + r0] * 0.125f : -10000.0f;
  float s1 = (g2.y != -1) ? S[tk * SP + r1] * 0.125f : -10000.0f;
  float m = fmaxf(s0, s1);
  m = fmaxf(m, __shfl_xor(m, 16, 64));
  m = fmaxf(m, __shfl_xor(m, 32, 64));
  float p0 = __expf(s0 - m), p1 = __expf(s1 - m);
  float den = p0 + p1;
  den += __shfl_xor(den, 16, 64);
  den += __shfl_xor(den, 32, 64);
  float inv = 1.0f / den;
  p0 *= inv; p1 *= inv;

  // ---- gather all 8 (p, rid) of this token via xor-shuffles
  float pb0 = __shfl_xor(p0, 16, 64), pb1 = __shfl_xor(p1, 16, 64);
  int   rb0 = __shfl_xor(r0, 16, 64), rb1 = __shfl_xor(r1, 16, 64);
  float pc0 = __shfl_xor(p0, 32, 64), pc1 = __shfl_xor(p1, 32, 64);
  int   rc0 = __shfl_xor(r0, 32, 64), rc1 = __shfl_xor(r1, 32, 64);
  float pd0 = __shfl_xor(p0, 48, 64), pd1 = __shfl_xor(p1, 48, 64);
  int   rd0 = __shfl_xor(r0, 48, 64), rd1 = __shfl_xor(r1, 48, 64);

  // ---- PV: lane owns dims [sub*16, sub*16+16) of this head
  const ushort* vb = Vtab + head * DH + sub * 16;
  float c[16];
  #pragma unroll
  for (int d = 0; d < 16; ++d) c[d] = 0.f;
  #define PV_ACC(P, R)                                                \
    {                                                                 \
      short8 v0 = *(const short8*)(vb + (size_t)(R) * H);             \
      short8 v1 = *(const short8*)(vb + (size_t)(R) * H + 8);         \
      _Pragma("unroll")                                               \
      for (int d = 0; d < 8; ++d) c[d]     += (P) * bf2f((ushort)v0[d]); \
      _Pragma("unroll")                                               \
      for (int d = 0; d < 8; ++d) c[d + 8] += (P) * bf2f((ushort)v1[d]); \
    }
  PV_ACC(p0,  r0)  PV_ACC(p1,  r1)
  PV_ACC(pb0, rb0) PV_ACC(pb1, rb1)
  PV_ACC(pc0, rc0) PV_ACC(pc1, rc1)
  PV_ACC(pd0, rd0) PV_ACC(pd1, rd1)
  #undef PV_ACC

  short8 o0, o1;
  #pragma unroll
  for (int d = 0; d < 8; ++d) { o0[d] = (short)f2bf(c[d]); o1[d] = (short)f2bf(c[d + 8]); }
  ushort* cp = Ctx + (size_t)t * H + head * DH + sub * 16;
  *(short8*)(cp) = o0;
  *(short8*)(cp + 8) = o1;
}

// ------------------------------------------------------- residual + LayerNorm
__global__ __launch_bounds__(256) void ln_kernel(
    const float* __restrict__ text, const ushort* __restrict__ op,
    const float* __restrict__ gamma, const float* __restrict__ beta,
    float* __restrict__ out) {
  int t = blockIdx.x;
  const float* xr = text + (size_t)t * H;
  const ushort* orow = op + (size_t)t * H;
  float x[3]; float s = 0.f, s2 = 0.f;
  #pragma unroll
  for (int jj = 0; jj < 3; ++jj) {
    int c = threadIdx.x + jj * 256;
    float v = xr[c] + bf2f(orow[c]);
    x[jj] = v; s += v; s2 += v * v;
  }
  #pragma unroll
  for (int off = 32; off > 0; off >>= 1) {
    s  += __shfl_xor(s, off, 64);
    s2 += __shfl_xor(s2, off, 64);
  }
  __shared__ float red[2][4];
  int wave = threadIdx.x >> 6, lane = threadIdx.x & 63;
  if (lane == 0) { red[0][wave] = s; red[1][wave] = s2; }
  __syncthreads();
  s  = red[0][0] + red[0][1] + red[0][2] + red[0][3];
  s2 = red[1][0] + red[1][1] + red[1][2] + red[1][3];
  float mu = s * (1.f / H);
  float var = s2 * (1.f / H) - mu * mu;
  float rs = rsqrtf(var + 1e-5f);
  #pragma unroll
  for (int jj = 0; jj < 3; ++jj) {
    int c = threadIdx.x + jj * 256;
    out[(size_t)t * H + c] = (x[jj] - mu) * rs * gamma[c] + beta[c];
  }
}

// ---------------------------------------------------------------------- driver
extern "C" void kernel_launch(void* const* d_in, const int* in_sizes, int n_in,
                              void* d_out, int out_size, void* d_ws, size_t ws_size,
                              hipStream_t stream) {
  const float* text      = (const float*)d_in[0];
  const int*   graph     = (const int*)d_in[1];
  const int*   relid     = (const int*)d_in[2];
  const float* rel_table = (const float*)d_in[3];
  const float* Wq = (const float*)d_in[4];  const float* bq = (const float*)d_in[5];
  const float* Wk = (const float*)d_in[6];  const float* bk = (const float*)d_in[7];
  const float* Wv = (const float*)d_in[8];  const float* bv = (const float*)d_in[9];
  const float* Wo = (const float*)d_in[10]; const float* bo = (const float*)d_in[11];
  const float* gamma = (const float*)d_in[12];
  const float* beta  = (const float*)d_in[13];
  float* out = (float*)d_out;
  char* ws = (char*)d_ws;

  const size_t TOKH = (size_t)NTOK * H;           // 12,582,912
  size_t off = 0;
  ushort* Xbf  = (ushort*)(ws + off); off += TOKH * 2;             // 25.2 MB; reused as Ctx
  ushort* Qbf  = (ushort*)(ws + off); off += TOKH * 2;             // 25.2 MB; reused as OutProj
  ushort* WqT  = (ushort*)(ws + off); off += (size_t)H * H * 2;    // 1.18 MB
  ushort* WoT  = (ushort*)(ws + off); off += (size_t)H * H * 2;
  ushort* WkT  = (ushort*)(ws + off); off += (size_t)H * H * 2;
  ushort* WvT  = (ushort*)(ws + off); off += (size_t)H * H * 2;
  ushort* RelB = (ushort*)(ws + off); off += (size_t)NRELP * H * 2;  // 196 KB
  ushort* Ktab = (ushort*)(ws + off); off += (size_t)NRELP * H * 2;
  ushort* Vtab = (ushort*)(ws + off); off += (size_t)NRELP * H * 2;

  // 1) X -> bf16; rel_table -> padded bf16
  cvt_kernel<<<TOKH / 1024, 256, 0, stream>>>(text, Xbf);
  rel_cvt_kernel<<<(NRELP * H) / 256, 256, 0, stream>>>(rel_table, RelB);
  // 2) transpose weights -> bf16 [N][K]
  dim3 tg(H / 32, H / 32);
  transpose_bf16_kernel<<<tg, 256, 0, stream>>>(Wq, WqT);
  transpose_bf16_kernel<<<tg, 256, 0, stream>>>(Wo, WoT);
  transpose_bf16_kernel<<<tg, 256, 0, stream>>>(Wk, WkT);
  transpose_bf16_kernel<<<tg, 256, 0, stream>>>(Wv, WvT);
  // 3) K/V tables via MFMA: [128][768] @ [768][768]^T
  dim3 gkv(H / BN, NRELP / BM);
  gemm_bt_kernel<<<gkv, 256, 0, stream>>>(RelB, WkT, bk, Ktab, NRELP, H, H);
  gemm_bt_kernel<<<gkv, 256, 0, stream>>>(RelB, WvT, bv, Vtab, NRELP, H, H);
  // 4) Q = Xbf @ WqT^T + bq
  dim3 g1(H / BN, NTOK / BM);
  gemm_bt_kernel<<<g1, 256, 0, stream>>>(Xbf, WqT, bq, Qbf, NTOK, H, H);
  // 5) attention -> Ctx (reuse Xbf storage)
  dim3 ga(NTOK / 64, NH);
  attn2_kernel<<<ga, 256, 0, stream>>>(Qbf, Ktab, Vtab, graph, relid, Xbf);
  // 6) OutProj = Ctx @ WoT^T + bo (reuse Qbf storage)
  gemm_bt_kernel<<<g1, 256, 0, stream>>>(Xbf, WoT, bo, Qbf, NTOK, H, H);
  // 7) residual + LayerNorm -> out
  ln_kernel<<<NTOK, 256, 0, stream>>>(text, Qbf, gamma, beta, out);
}

// Round 4
// 169.237 us; speedup vs baseline: 1.1730x; 1.1730x over previous
//
#include <hip/hip_runtime.h>
#include <hip/hip_bf16.h>

#define H 768
#define NH 12
#define DH 64
#define LL 8
#define NTOK 16384   // B*S = 8*2048
#define NREL 100
#define NRELP 128    // padded to BM for the K/V-table GEMM
#define PADW 72      // LDS row stride in bf16 (144 B = 9 x 16B chunks)

typedef __attribute__((ext_vector_type(8))) short short8;
typedef __attribute__((ext_vector_type(4))) float f32x4;

__device__ __forceinline__ float bf2f(ushort u) {
  union { unsigned int i; float f; } v; v.i = ((unsigned int)u) << 16; return v.f;
}
__device__ __forceinline__ float bflo(unsigned int u) {
  union { unsigned int i; float f; } v; v.i = u << 16; return v.f;
}
__device__ __forceinline__ float bfhi(unsigned int u) {
  union { unsigned int i; float f; } v; v.i = u & 0xffff0000u; return v.f;
}
__device__ __forceinline__ ushort f2bf(float f) {
  union { float f; unsigned int i; } v; v.f = f;
  unsigned int x = v.i;
  return (ushort)((x + 0x7fffu + ((x >> 16) & 1u)) >> 16);  // RNE
}

// ---------------------------------------------------------------- cvt f32->bf16
__global__ __launch_bounds__(256) void cvt_kernel(const float* __restrict__ src,
                                                  ushort* __restrict__ dst) {
  int i = (blockIdx.x * 256 + threadIdx.x) * 4;
  float4 v = *(const float4*)(src + i);
  ushort4 o; o.x = f2bf(v.x); o.y = f2bf(v.y); o.z = f2bf(v.z); o.w = f2bf(v.w);
  *(ushort4*)(dst + i) = o;
}

// -------------------------------- rel_table [100][768] f32 -> [128][768] bf16
__global__ __launch_bounds__(256) void rel_cvt_kernel(const float* __restrict__ src,
                                                      ushort* __restrict__ dst) {
  int i = blockIdx.x * 256 + threadIdx.x;      // 0 .. 128*768-1
  int row = i / H;
  dst[i] = (row < NREL) ? f2bf(src[i]) : (ushort)0;
}

// ------------------------------------------------- transpose [H][H] f32 -> bf16
__global__ __launch_bounds__(256) void transpose_bf16_kernel(const float* __restrict__ src,
                                                             ushort* __restrict__ dst) {
  __shared__ float tile[32][33];
  int bx = blockIdx.x * 32, by = blockIdx.y * 32;
  int tx = threadIdx.x & 31, ty = threadIdx.x >> 5;  // ty 0..7
  #pragma unroll
  for (int i = 0; i < 32; i += 8)
    tile[ty + i][tx] = src[(size_t)(by + ty + i) * H + bx + tx];
  __syncthreads();
  #pragma unroll
  for (int i = 0; i < 32; i += 8)
    dst[(size_t)(bx + ty + i) * H + by + tx] = f2bf(tile[tx][ty + i]);
}

// ------------------------------------------------------------- bf16 MFMA GEMM
// C[M][N] = A[M][K] @ Bt[N][K]^T + bias, all bf16 in / bf16 out, fp32 accum.
__device__ __forceinline__ void gload_lds16(const void* g, void* l) {
  __builtin_amdgcn_global_load_lds(
      (const __attribute__((address_space(1))) unsigned int*)g,
      (__attribute__((address_space(3))) unsigned int*)l, 16, 0, 0);
}

#define BM 128
#define BN 128
#define BK 32

__global__ __launch_bounds__(256, 2) void gemm_bt_kernel(
    const ushort* __restrict__ A,    // [M][K]
    const ushort* __restrict__ Bt,   // [N][K]
    const float* __restrict__ bias,  // [N]
    ushort* __restrict__ C,          // [M][N]
    int M, int N, int K) {
  __shared__ ushort As[BM * BK];   // 8 KB, row-major [BM][BK]
  __shared__ ushort Bs[BN * BK];   // 8 KB
  const int tid = threadIdx.x;
  const int row0 = blockIdx.y * BM;
  const int col0 = blockIdx.x * BN;
  const int wave = tid >> 6;
  const int lane = tid & 63;
  const int wr = wave >> 1, wc = wave & 1;     // 2x2 waves, 64x64 each
  const int lr = lane & 15, lk = lane >> 4;    // frag row/col & k-group
  f32x4 acc[4][4];
  #pragma unroll
  for (int m = 0; m < 4; ++m)
    #pragma unroll
    for (int n = 0; n < 4; ++n) acc[m][n] = (f32x4)(0.f);

  for (int k0 = 0; k0 < K; k0 += BK) {
    #pragma unroll
    for (int i = 0; i < 2; ++i) {
      int c = tid + i * 256;        // 16B chunk id, 512 chunks per 8KB tile
      int r = c >> 2, q = c & 3;    // tile row, quarter-row (8 bf16)
      gload_lds16(A  + (size_t)(row0 + r) * K + k0 + q * 8, (char*)As + c * 16);
      gload_lds16(Bt + (size_t)(col0 + r) * K + k0 + q * 8, (char*)Bs + c * 16);
    }
    __syncthreads();
    short8 af[4], bfr[4];
    #pragma unroll
    for (int m = 0; m < 4; ++m)
      af[m] = *(const short8*)(As + (wr * 64 + m * 16 + lr) * BK + lk * 8);
    #pragma unroll
    for (int n = 0; n < 4; ++n)
      bfr[n] = *(const short8*)(Bs + (wc * 64 + n * 16 + lr) * BK + lk * 8);
    #pragma unroll
    for (int m = 0; m < 4; ++m)
      #pragma unroll
      for (int n = 0; n < 4; ++n)
        acc[m][n] = __builtin_amdgcn_mfma_f32_16x16x32_bf16(af[m], bfr[n], acc[m][n], 0, 0, 0);
    __syncthreads();
  }
  // epilogue: C/D layout col = lane&15, row = (lane>>4)*4 + j  [verified m89/m91]
  #pragma unroll
  for (int m = 0; m < 4; ++m) {
    #pragma unroll
    for (int n = 0; n < 4; ++n) {
      int col = col0 + wc * 64 + n * 16 + lr;
      float b = bias[col];
      #pragma unroll
      for (int j = 0; j < 4; ++j) {
        int row = row0 + wr * 64 + m * 16 + lk * 4 + j;
        C[(size_t)row * N + col] = f2bf(acc[m][n][j] + b);
      }
    }
  }
}

// ---------------------------------------------- gather-form GAT attention (v3)
// One lane per (token, head). K/V head-slices staged once per block in LDS
// (rows 0..99, stride 72 bf16 so row starts spread across 8 bank groups).
// Zero cross-lane ops, one barrier. 256 tokens x 1 head per block.
__global__ __launch_bounds__(256) void attn3_kernel(
    const ushort* __restrict__ Q,     // [NTOK][H] bf16
    const ushort* __restrict__ Ktab,  // [NRELP][H] bf16
    const ushort* __restrict__ Vtab,  // [NRELP][H] bf16
    const int* __restrict__ graph,    // [NTOK][LL]
    const int* __restrict__ relid,    // [NTOK][LL]
    ushort* __restrict__ Ctx) {       // [NTOK][H] bf16
  __shared__ __align__(16) ushort Ks[NREL * PADW];  // 14.4 KB
  __shared__ __align__(16) ushort Vs[NREL * PADW];  // 14.4 KB
  const int tid = threadIdx.x;
  const int head = blockIdx.y;
  const int t = blockIdx.x * 256 + tid;

  // ---- stage K/V head slices: 900 16B chunks each (9 per row, slot 8 = pad)
  #pragma unroll
  for (int i = 0; i < 4; ++i) {
    int c = tid + i * 256;
    if (c < NREL * 9) {
      int row = c / 9, slot = c - row * 9;
      int gs = (slot < 8) ? slot * 8 : 0;        // pad chunk: load row base (safe dup)
      const size_t src = (size_t)row * H + head * DH + gs;
      gload_lds16(Ktab + src, (char*)Ks + (size_t)c * 16);
      gload_lds16(Vtab + src, (char*)Vs + (size_t)c * 16);
    }
  }

  // ---- while staging is in flight: load q (128 B), graph, relid
  const uint4* qp = (const uint4*)(Q + (size_t)t * H + head * DH);
  uint4 qw[8];
  #pragma unroll
  for (int j = 0; j < 8; ++j) qw[j] = qp[j];
  const int4* gp = (const int4*)(graph + (size_t)t * LL);
  const int4* rp = (const int4*)(relid + (size_t)t * LL);
  int4 ga = gp[0], gb = gp[1];
  int4 ra = rp[0], rb = rp[1];
  int gs[8] = {ga.x, ga.y, ga.z, ga.w, gb.x, gb.y, gb.z, gb.w};
  int rid[8] = {ra.x, ra.y, ra.z, ra.w, rb.x, rb.y, rb.z, rb.w};
  int koff[8];
  #pragma unroll
  for (int l = 0; l < 8; ++l) {
    int r = rid[l] < 0 ? 0 : rid[l];
    koff[l] = r * (PADW * 2);                    // byte offset of row r
  }

  __syncthreads();   // drains gload_lds (vmcnt) + barrier

  // ---- QK: s[l] = dot64(q, K[rid[l]]) ; j-outer over 8-dim blocks
  float s[8];
  #pragma unroll
  for (int l = 0; l < 8; ++l) s[l] = 0.f;
  #pragma unroll
  for (int j = 0; j < 8; ++j) {
    float qf[8];
    qf[0] = bflo(qw[j].x); qf[1] = bfhi(qw[j].x);
    qf[2] = bflo(qw[j].y); qf[3] = bfhi(qw[j].y);
    qf[4] = bflo(qw[j].z); qf[5] = bfhi(qw[j].z);
    qf[6] = bflo(qw[j].w); qf[7] = bfhi(qw[j].w);
    #pragma unroll
    for (int l = 0; l < 8; ++l) {
      uint4 kw = *(const uint4*)((const char*)Ks + koff[l] + j * 16);
      s[l] += qf[0] * bflo(kw.x) + qf[1] * bfhi(kw.x)
            + qf[2] * bflo(kw.y) + qf[3] * bfhi(kw.y)
            + qf[4] * bflo(kw.z) + qf[5] * bfhi(kw.z)
            + qf[6] * bflo(kw.w) + qf[7] * bfhi(kw.w);
    }
  }

  // ---- softmax over 8 leaves (all in-register)
  #pragma unroll
  for (int l = 0; l < 8; ++l)
    s[l] = (gs[l] != -1) ? s[l] * 0.125f : -10000.0f;
  float mx = s[0];
  #pragma unroll
  for (int l = 1; l < 8; ++l) mx = fmaxf(mx, s[l]);
  float p[8], den = 0.f;
  #pragma unroll
  for (int l = 0; l < 8; ++l) { p[l] = __expf(s[l] - mx); den += p[l]; }
  float inv = 1.f / den;
  #pragma unroll
  for (int l = 0; l < 8; ++l) p[l] *= inv;

  // ---- PV: ctx[d] = sum_l p[l] * V[rid[l]][d] ; j-outer, 8 dims at a time
  ushort* cp = Ctx + (size_t)t * H + head * DH;
  #pragma unroll
  for (int j = 0; j < 8; ++j) {
    float a[8];
    #pragma unroll
    for (int d = 0; d < 8; ++d) a[d] = 0.f;
    #pragma unroll
    for (int l = 0; l < 8; ++l) {
      uint4 vw = *(const uint4*)((const char*)Vs + koff[l] + j * 16);
      a[0] += p[l] * bflo(vw.x); a[1] += p[l] * bfhi(vw.x);
      a[2] += p[l] * bflo(vw.y); a[3] += p[l] * bfhi(vw.y);
      a[4] += p[l] * bflo(vw.z); a[5] += p[l] * bfhi(vw.z);
      a[6] += p[l] * bflo(vw.w); a[7] += p[l] * bfhi(vw.w);
    }
    short8 o;
    #pragma unroll
    for (int d = 0; d < 8; ++d) o[d] = (short)f2bf(a[d]);
    *(short8*)(cp + j * 8) = o;
  }
}

// ------------------------------------------------------- residual + LayerNorm
__global__ __launch_bounds__(256) void ln_kernel(
    const float* __restrict__ text, const ushort* __restrict__ op,
    const float* __restrict__ gamma, const float* __restrict__ beta,
    float* __restrict__ out) {
  int t = blockIdx.x;
  const float* xr = text + (size_t)t * H;
  const ushort* orow = op + (size_t)t * H;
  float x[3]; float s = 0.f, s2 = 0.f;
  #pragma unroll
  for (int jj = 0; jj < 3; ++jj) {
    int c = threadIdx.x + jj * 256;
    float v = xr[c] + bf2f(orow[c]);
    x[jj] = v; s += v; s2 += v * v;
  }
  #pragma unroll
  for (int off = 32; off > 0; off >>= 1) {
    s  += __shfl_xor(s, off, 64);
    s2 += __shfl_xor(s2, off, 64);
  }
  __shared__ float red[2][4];
  int wave = threadIdx.x >> 6, lane = threadIdx.x & 63;
  if (lane == 0) { red[0][wave] = s; red[1][wave] = s2; }
  __syncthreads();
  s  = red[0][0] + red[0][1] + red[0][2] + red[0][3];
  s2 = red[1][0] + red[1][1] + red[1][2] + red[1][3];
  float mu = s * (1.f / H);
  float var = s2 * (1.f / H) - mu * mu;
  float rs = rsqrtf(var + 1e-5f);
  #pragma unroll
  for (int jj = 0; jj < 3; ++jj) {
    int c = threadIdx.x + jj * 256;
    out[(size_t)t * H + c] = (x[jj] - mu) * rs * gamma[c] + beta[c];
  }
}

// ---------------------------------------------------------------------- driver
extern "C" void kernel_launch(void* const* d_in, const int* in_sizes, int n_in,
                              void* d_out, int out_size, void* d_ws, size_t ws_size,
                              hipStream_t stream) {
  const float* text      = (const float*)d_in[0];
  const int*   graph     = (const int*)d_in[1];
  const int*   relid     = (const int*)d_in[2];
  const float* rel_table = (const float*)d_in[3];
  const float* Wq = (const float*)d_in[4];  const float* bq = (const float*)d_in[5];
  const float* Wk = (const float*)d_in[6];  const float* bk = (const float*)d_in[7];
  const float* Wv = (const float*)d_in[8];  const float* bv = (const float*)d_in[9];
  const float* Wo = (const float*)d_in[10]; const float* bo = (const float*)d_in[11];
  const float* gamma = (const float*)d_in[12];
  const float* beta  = (const float*)d_in[13];
  float* out = (float*)d_out;
  char* ws = (char*)d_ws;

  const size_t TOKH = (size_t)NTOK * H;           // 12,582,912
  size_t off = 0;
  ushort* Xbf  = (ushort*)(ws + off); off += TOKH * 2;             // 25.2 MB; reused as Ctx
  ushort* Qbf  = (ushort*)(ws + off); off += TOKH * 2;             // 25.2 MB; reused as OutProj
  ushort* WqT  = (ushort*)(ws + off); off += (size_t)H * H * 2;    // 1.18 MB
  ushort* WoT  = (ushort*)(ws + off); off += (size_t)H * H * 2;
  ushort* WkT  = (ushort*)(ws + off); off += (size_t)H * H * 2;
  ushort* WvT  = (ushort*)(ws + off); off += (size_t)H * H * 2;
  ushort* RelB = (ushort*)(ws + off); off += (size_t)NRELP * H * 2;  // 196 KB
  ushort* Ktab = (ushort*)(ws + off); off += (size_t)NRELP * H * 2;
  ushort* Vtab = (ushort*)(ws + off); off += (size_t)NRELP * H * 2;

  // 1) X -> bf16; rel_table -> padded bf16
  cvt_kernel<<<TOKH / 1024, 256, 0, stream>>>(text, Xbf);
  rel_cvt_kernel<<<(NRELP * H) / 256, 256, 0, stream>>>(rel_table, RelB);
  // 2) transpose weights -> bf16 [N][K]
  dim3 tg(H / 32, H / 32);
  transpose_bf16_kernel<<<tg, 256, 0, stream>>>(Wq, WqT);
  transpose_bf16_kernel<<<tg, 256, 0, stream>>>(Wo, WoT);
  transpose_bf16_kernel<<<tg, 256, 0, stream>>>(Wk, WkT);
  transpose_bf16_kernel<<<tg, 256, 0, stream>>>(Wv, WvT);
  // 3) K/V tables via MFMA: [128][768] @ [768][768]^T
  dim3 gkv(H / BN, NRELP / BM);
  gemm_bt_kernel<<<gkv, 256, 0, stream>>>(RelB, WkT, bk, Ktab, NRELP, H, H);
  gemm_bt_kernel<<<gkv, 256, 0, stream>>>(RelB, WvT, bv, Vtab, NRELP, H, H);
  // 4) Q = Xbf @ WqT^T + bq
  dim3 g1(H / BN, NTOK / BM);
  gemm_bt_kernel<<<g1, 256, 0, stream>>>(Xbf, WqT, bq, Qbf, NTOK, H, H);
  // 5) attention -> Ctx (reuse Xbf storage)
  dim3 ga(NTOK / 256, NH);
  attn3_kernel<<<ga, 256, 0, stream>>>(Qbf, Ktab, Vtab, graph, relid, Xbf);
  // 6) OutProj = Ctx @ WoT^T + bo (reuse Qbf storage)
  gemm_bt_kernel<<<g1, 256, 0, stream>>>(Xbf, WoT, bo, Qbf, NTOK, H, H);
  // 7) residual + LayerNorm -> out
  ln_kernel<<<NTOK, 256, 0, stream>>>(text, Qbf, gamma, beta, out);
}

// Round 5
// 123.973 us; speedup vs baseline: 1.6013x; 1.3651x over previous
//
#include <hip/hip_runtime.h>
#include <hip/hip_bf16.h>

#define H 768
#define NH 12
#define DH 64
#define LL 8
#define NTOK 16384   // B*S = 8*2048
#define NREL 100
#define NRELP 128    // padded to BM for the K/V-table GEMM
#define PADW 72      // attn LDS row stride in bf16 (144 B = 9 x 16B chunks)

typedef __attribute__((ext_vector_type(8))) short short8;
typedef __attribute__((ext_vector_type(4))) float f32x4;

__device__ __forceinline__ float bf2f(ushort u) {
  union { unsigned int i; float f; } v; v.i = ((unsigned int)u) << 16; return v.f;
}
__device__ __forceinline__ float bflo(unsigned int u) {
  union { unsigned int i; float f; } v; v.i = u << 16; return v.f;
}
__device__ __forceinline__ float bfhi(unsigned int u) {
  union { unsigned int i; float f; } v; v.i = u & 0xffff0000u; return v.f;
}
__device__ __forceinline__ ushort f2bf(float f) {
  union { float f; unsigned int i; } v; v.f = f;
  unsigned int x = v.i;
  return (ushort)((x + 0x7fffu + ((x >> 16) & 1u)) >> 16);  // RNE
}

// --------------------------- fused cvt: X f32->bf16, rel_table -> padded bf16
#define NBX 12288   // NTOK*H/1024
#define NBR 96      // NRELP*H/1024
__global__ __launch_bounds__(256) void cvt_all_kernel(
    const float* __restrict__ X, ushort* __restrict__ Xbf,
    const float* __restrict__ rel, ushort* __restrict__ RelB) {
  int b = blockIdx.x;
  if (b < NBX) {
    int i = (b * 256 + threadIdx.x) * 4;
    float4 v = *(const float4*)(X + i);
    ushort4 o; o.x = f2bf(v.x); o.y = f2bf(v.y); o.z = f2bf(v.z); o.w = f2bf(v.w);
    *(ushort4*)(Xbf + i) = o;
  } else {
    int i = ((b - NBX) * 256 + threadIdx.x) * 4;   // < NRELP*H, 4-chunk stays in-row
    int row = i / H;
    ushort4 o = {0, 0, 0, 0};
    if (row < NREL) {
      float4 v = *(const float4*)(rel + i);
      o.x = f2bf(v.x); o.y = f2bf(v.y); o.z = f2bf(v.z); o.w = f2bf(v.w);
    }
    *(ushort4*)(RelB + i) = o;
  }
}

// --------------------------- 4 weight transposes [H][H] f32 -> bf16, one launch
__global__ __launch_bounds__(256) void transpose4_kernel(
    const float* __restrict__ s0, ushort* __restrict__ d0,
    const float* __restrict__ s1, ushort* __restrict__ d1,
    const float* __restrict__ s2, ushort* __restrict__ d2,
    const float* __restrict__ s3, ushort* __restrict__ d3) {
  const float* src; ushort* dst;
  switch (blockIdx.z) {
    case 0:  src = s0; dst = d0; break;
    case 1:  src = s1; dst = d1; break;
    case 2:  src = s2; dst = d2; break;
    default: src = s3; dst = d3; break;
  }
  __shared__ float tile[32][33];
  int bx = blockIdx.x * 32, by = blockIdx.y * 32;
  int tx = threadIdx.x & 31, ty = threadIdx.x >> 5;  // ty 0..7
  #pragma unroll
  for (int i = 0; i < 32; i += 8)
    tile[ty + i][tx] = src[(size_t)(by + ty + i) * H + bx + tx];
  __syncthreads();
  #pragma unroll
  for (int i = 0; i < 32; i += 8)
    dst[(size_t)(bx + ty + i) * H + by + tx] = f2bf(tile[tx][ty + i]);
}

// ------------------------------------------------------------- bf16 MFMA GEMM
// C[M][N] = A[M][K] @ Bt[N][K]^T + bias. BK=64, XOR-swizzled LDS (T2 both-sides):
// linear LDS dest, global source seg gs = slot^(row&7), ds_read slot sw = q^(lr&7).
__device__ __forceinline__ void gload_lds16(const void* g, void* l) {
  __builtin_amdgcn_global_load_lds(
      (const __attribute__((address_space(1))) unsigned int*)g,
      (__attribute__((address_space(3))) unsigned int*)l, 16, 0, 0);
}

#define BM 128
#define BN 128
#define BK 64

__device__ __forceinline__ void gemm_body(
    const ushort* __restrict__ A,    // [M][K]
    const ushort* __restrict__ Bt,   // [N][K]
    const float* __restrict__ bias,  // [N]
    ushort* __restrict__ C,          // [M][N]
    int M, int N, int K, int bx, int by) {
  __shared__ ushort As[BM * BK];   // 16 KB, [128 rows][8 slots of 16B], swizzled
  __shared__ ushort Bs[BN * BK];   // 16 KB
  const int tid = threadIdx.x;
  const int row0 = by * BM;
  const int col0 = bx * BN;
  const int wave = tid >> 6;
  const int lane = tid & 63;
  const int wr = wave >> 1, wc = wave & 1;     // 2x2 waves, 64x64 each
  const int lr = lane & 15, lk = lane >> 4;    // frag row & k-group
  f32x4 acc[4][4];
  #pragma unroll
  for (int m = 0; m < 4; ++m)
    #pragma unroll
    for (int n = 0; n < 4; ++n) acc[m][n] = (f32x4)(0.f);

  for (int k0 = 0; k0 < K; k0 += BK) {
    #pragma unroll
    for (int i = 0; i < 4; ++i) {
      int c = tid + i * 256;         // 16B chunk id, 1024 chunks per 16KB tile
      int r = c >> 3, s = c & 7;
      int gs = s ^ (r & 7);          // inverse swizzle on global source
      gload_lds16(A  + (size_t)(row0 + r) * K + k0 + gs * 8, (char*)As + c * 16);
      gload_lds16(Bt + (size_t)(col0 + r) * K + k0 + gs * 8, (char*)Bs + c * 16);
    }
    __syncthreads();
    #pragma unroll
    for (int kk = 0; kk < 2; ++kk) {
      const int sw = (((kk << 2) | lk) ^ (lr & 7)) * 8;  // swizzled 8-elem slot
      short8 af[4], bfr[4];
      #pragma unroll
      for (int m = 0; m < 4; ++m)
        af[m] = *(const short8*)(As + (wr * 64 + m * 16 + lr) * BK + sw);
      #pragma unroll
      for (int n = 0; n < 4; ++n)
        bfr[n] = *(const short8*)(Bs + (wc * 64 + n * 16 + lr) * BK + sw);
      #pragma unroll
      for (int m = 0; m < 4; ++m)
        #pragma unroll
        for (int n = 0; n < 4; ++n)
          acc[m][n] = __builtin_amdgcn_mfma_f32_16x16x32_bf16(af[m], bfr[n], acc[m][n], 0, 0, 0);
    }
    __syncthreads();
  }
  // epilogue: C/D layout col = lane&15, row = (lane>>4)*4 + j  [verified m89/m91]
  #pragma unroll
  for (int m = 0; m < 4; ++m) {
    #pragma unroll
    for (int n = 0; n < 4; ++n) {
      int col = col0 + wc * 64 + n * 16 + lr;
      float b = bias[col];
      #pragma unroll
      for (int j = 0; j < 4; ++j) {
        int row = row0 + wr * 64 + m * 16 + lk * 4 + j;
        C[(size_t)row * N + col] = f2bf(acc[m][n][j] + b);
      }
    }
  }
}

// big GEMM: bijective XCD swizzle over the full grid (nwg % 8 == 0 by construction)
__global__ __launch_bounds__(256, 2) void gemm_bt_kernel(
    const ushort* __restrict__ A, const ushort* __restrict__ Bt,
    const float* __restrict__ bias, ushort* __restrict__ C,
    int M, int N, int K) {
  int lin = blockIdx.y * gridDim.x + blockIdx.x;
  int q = (gridDim.x * gridDim.y) >> 3;
  int wg = (lin & 7) * q + (lin >> 3);
  gemm_body(A, Bt, bias, C, M, N, K, wg % gridDim.x, wg / gridDim.x);
}

// K/V tables in one launch: z=0 -> K, z=1 -> V
__global__ __launch_bounds__(256, 2) void gemm_kv_kernel(
    const ushort* __restrict__ A,
    const ushort* __restrict__ BtK, const float* __restrict__ bK, ushort* __restrict__ CK,
    const ushort* __restrict__ BtV, const float* __restrict__ bV, ushort* __restrict__ CV) {
  if (blockIdx.z == 0)
    gemm_body(A, BtK, bK, CK, NRELP, H, H, blockIdx.x, blockIdx.y);
  else
    gemm_body(A, BtV, bV, CV, NRELP, H, H, blockIdx.x, blockIdx.y);
}

// ---------------------------------------------- gather-form GAT attention (v3)
// One lane per (token, head). K/V head-slices staged once per block in LDS
// (rows 0..99, stride 72 bf16). Zero cross-lane ops, one barrier.
__global__ __launch_bounds__(256) void attn3_kernel(
    const ushort* __restrict__ Q,     // [NTOK][H] bf16
    const ushort* __restrict__ Ktab,  // [NRELP][H] bf16
    const ushort* __restrict__ Vtab,  // [NRELP][H] bf16
    const int* __restrict__ graph,    // [NTOK][LL]
    const int* __restrict__ relid,    // [NTOK][LL]
    ushort* __restrict__ Ctx) {       // [NTOK][H] bf16
  __shared__ __align__(16) ushort Ks[NREL * PADW];  // 14.4 KB
  __shared__ __align__(16) ushort Vs[NREL * PADW];  // 14.4 KB
  const int tid = threadIdx.x;
  const int head = blockIdx.y;
  const int t = blockIdx.x * 256 + tid;

  #pragma unroll
  for (int i = 0; i < 4; ++i) {
    int c = tid + i * 256;
    if (c < NREL * 9) {
      int row = c / 9, slot = c - row * 9;
      int gs = (slot < 8) ? slot * 8 : 0;        // pad chunk: safe dup
      const size_t src = (size_t)row * H + head * DH + gs;
      gload_lds16(Ktab + src, (char*)Ks + (size_t)c * 16);
      gload_lds16(Vtab + src, (char*)Vs + (size_t)c * 16);
    }
  }

  const uint4* qp = (const uint4*)(Q + (size_t)t * H + head * DH);
  uint4 qw[8];
  #pragma unroll
  for (int j = 0; j < 8; ++j) qw[j] = qp[j];
  const int4* gp = (const int4*)(graph + (size_t)t * LL);
  const int4* rp = (const int4*)(relid + (size_t)t * LL);
  int4 ga = gp[0], gb = gp[1];
  int4 ra = rp[0], rb = rp[1];
  int gs[8] = {ga.x, ga.y, ga.z, ga.w, gb.x, gb.y, gb.z, gb.w};
  int rid[8] = {ra.x, ra.y, ra.z, ra.w, rb.x, rb.y, rb.z, rb.w};
  int koff[8];
  #pragma unroll
  for (int l = 0; l < 8; ++l) {
    int r = rid[l] < 0 ? 0 : rid[l];
    koff[l] = r * (PADW * 2);
  }

  __syncthreads();

  float s[8];
  #pragma unroll
  for (int l = 0; l < 8; ++l) s[l] = 0.f;
  #pragma unroll
  for (int j = 0; j < 8; ++j) {
    float qf[8];
    qf[0] = bflo(qw[j].x); qf[1] = bfhi(qw[j].x);
    qf[2] = bflo(qw[j].y); qf[3] = bfhi(qw[j].y);
    qf[4] = bflo(qw[j].z); qf[5] = bfhi(qw[j].z);
    qf[6] = bflo(qw[j].w); qf[7] = bfhi(qw[j].w);
    #pragma unroll
    for (int l = 0; l < 8; ++l) {
      uint4 kw = *(const uint4*)((const char*)Ks + koff[l] + j * 16);
      s[l] += qf[0] * bflo(kw.x) + qf[1] * bfhi(kw.x)
            + qf[2] * bflo(kw.y) + qf[3] * bfhi(kw.y)
            + qf[4] * bflo(kw.z) + qf[5] * bfhi(kw.z)
            + qf[6] * bflo(kw.w) + qf[7] * bfhi(kw.w);
    }
  }

  #pragma unroll
  for (int l = 0; l < 8; ++l)
    s[l] = (gs[l] != -1) ? s[l] * 0.125f : -10000.0f;
  float mx = s[0];
  #pragma unroll
  for (int l = 1; l < 8; ++l) mx = fmaxf(mx, s[l]);
  float p[8], den = 0.f;
  #pragma unroll
  for (int l = 0; l < 8; ++l) { p[l] = __expf(s[l] - mx); den += p[l]; }
  float inv = 1.f / den;
  #pragma unroll
  for (int l = 0; l < 8; ++l) p[l] *= inv;

  ushort* cp = Ctx + (size_t)t * H + head * DH;
  #pragma unroll
  for (int j = 0; j < 8; ++j) {
    float a[8];
    #pragma unroll
    for (int d = 0; d < 8; ++d) a[d] = 0.f;
    #pragma unroll
    for (int l = 0; l < 8; ++l) {
      uint4 vw = *(const uint4*)((const char*)Vs + koff[l] + j * 16);
      a[0] += p[l] * bflo(vw.x); a[1] += p[l] * bfhi(vw.x);
      a[2] += p[l] * bflo(vw.y); a[3] += p[l] * bfhi(vw.y);
      a[4] += p[l] * bflo(vw.z); a[5] += p[l] * bfhi(vw.z);
      a[6] += p[l] * bflo(vw.w); a[7] += p[l] * bfhi(vw.w);
    }
    short8 o;
    #pragma unroll
    for (int d = 0; d < 8; ++d) o[d] = (short)f2bf(a[d]);
    *(short8*)(cp + j * 8) = o;
  }
}

// ------------------------------------- residual + LayerNorm (192 thr, float4)
__global__ __launch_bounds__(192) void ln_kernel(
    const float* __restrict__ text, const ushort* __restrict__ op,
    const float* __restrict__ gamma, const float* __restrict__ beta,
    float* __restrict__ out) {
  int t = blockIdx.x;
  int c0 = threadIdx.x * 4;
  float4 tv = *(const float4*)(text + (size_t)t * H + c0);
  ushort4 ov = *(const ushort4*)(op + (size_t)t * H + c0);
  float x0 = tv.x + bf2f(ov.x), x1 = tv.y + bf2f(ov.y);
  float x2 = tv.z + bf2f(ov.z), x3 = tv.w + bf2f(ov.w);
  float s = x0 + x1 + x2 + x3;
  float s2 = x0 * x0 + x1 * x1 + x2 * x2 + x3 * x3;
  #pragma unroll
  for (int off = 32; off > 0; off >>= 1) {
    s  += __shfl_xor(s, off, 64);
    s2 += __shfl_xor(s2, off, 64);
  }
  __shared__ float red[2][3];
  int wave = threadIdx.x >> 6, lane = threadIdx.x & 63;
  if (lane == 0) { red[0][wave] = s; red[1][wave] = s2; }
  __syncthreads();
  s  = red[0][0] + red[0][1] + red[0][2];
  s2 = red[1][0] + red[1][1] + red[1][2];
  float mu = s * (1.f / H);
  float var = s2 * (1.f / H) - mu * mu;
  float rs = rsqrtf(var + 1e-5f);
  float4 g4 = *(const float4*)(gamma + c0);
  float4 b4 = *(const float4*)(beta + c0);
  float4 o4;
  o4.x = (x0 - mu) * rs * g4.x + b4.x;
  o4.y = (x1 - mu) * rs * g4.y + b4.y;
  o4.z = (x2 - mu) * rs * g4.z + b4.z;
  o4.w = (x3 - mu) * rs * g4.w + b4.w;
  *(float4*)(out + (size_t)t * H + c0) = o4;
}

// ---------------------------------------------------------------------- driver
extern "C" void kernel_launch(void* const* d_in, const int* in_sizes, int n_in,
                              void* d_out, int out_size, void* d_ws, size_t ws_size,
                              hipStream_t stream) {
  const float* text      = (const float*)d_in[0];
  const int*   graph     = (const int*)d_in[1];
  const int*   relid     = (const int*)d_in[2];
  const float* rel_table = (const float*)d_in[3];
  const float* Wq = (const float*)d_in[4];  const float* bq = (const float*)d_in[5];
  const float* Wk = (const float*)d_in[6];  const float* bk = (const float*)d_in[7];
  const float* Wv = (const float*)d_in[8];  const float* bv = (const float*)d_in[9];
  const float* Wo = (const float*)d_in[10]; const float* bo = (const float*)d_in[11];
  const float* gamma = (const float*)d_in[12];
  const float* beta  = (const float*)d_in[13];
  float* out = (float*)d_out;
  char* ws = (char*)d_ws;

  const size_t TOKH = (size_t)NTOK * H;           // 12,582,912
  size_t off = 0;
  ushort* Xbf  = (ushort*)(ws + off); off += TOKH * 2;             // reused as Ctx
  ushort* Qbf  = (ushort*)(ws + off); off += TOKH * 2;             // reused as OutProj
  ushort* WqT  = (ushort*)(ws + off); off += (size_t)H * H * 2;
  ushort* WoT  = (ushort*)(ws + off); off += (size_t)H * H * 2;
  ushort* WkT  = (ushort*)(ws + off); off += (size_t)H * H * 2;
  ushort* WvT  = (ushort*)(ws + off); off += (size_t)H * H * 2;
  ushort* RelB = (ushort*)(ws + off); off += (size_t)NRELP * H * 2;
  ushort* Ktab = (ushort*)(ws + off); off += (size_t)NRELP * H * 2;
  ushort* Vtab = (ushort*)(ws + off); off += (size_t)NRELP * H * 2;

  // 1) X + rel_table -> bf16 (one launch)
  cvt_all_kernel<<<NBX + NBR, 256, 0, stream>>>(text, Xbf, rel_table, RelB);
  // 2) 4 weight transposes (one launch)
  transpose4_kernel<<<dim3(H / 32, H / 32, 4), 256, 0, stream>>>(
      Wq, WqT, Wo, WoT, Wk, WkT, Wv, WvT);
  // 3) K/V tables via MFMA (one launch)
  gemm_kv_kernel<<<dim3(H / BN, NRELP / BM, 2), 256, 0, stream>>>(
      RelB, WkT, bk, Ktab, WvT, bv, Vtab);
  // 4) Q = Xbf @ WqT^T + bq
  dim3 g1(H / BN, NTOK / BM);
  gemm_bt_kernel<<<g1, 256, 0, stream>>>(Xbf, WqT, bq, Qbf, NTOK, H, H);
  // 5) attention -> Ctx (reuse Xbf storage)
  dim3 ga(NTOK / 256, NH);
  attn3_kernel<<<ga, 256, 0, stream>>>(Qbf, Ktab, Vtab, graph, relid, Xbf);
  // 6) OutProj = Ctx @ WoT^T + bo (reuse Qbf storage)
  gemm_bt_kernel<<<g1, 256, 0, stream>>>(Xbf, WoT, bo, Qbf, NTOK, H, H);
  // 7) residual + LayerNorm -> out
  ln_kernel<<<NTOK, 192, 0, stream>>>(text, Qbf, gamma, beta, out);
}

// Round 6
// 109.710 us; speedup vs baseline: 1.8095x; 1.1300x over previous
//
#include <hip/hip_runtime.h>
#include <hip/hip_bf16.h>

#define H 768
#define NH 12
#define DH 64
#define LL 8
#define NTOK 16384   // B*S = 8*2048
#define NREL 100
#define NRELP 128    // padded to BM for the K/V-table GEMM
#define PADW 72      // attn LDS row stride in bf16 (144 B = 9 x 16B chunks)

typedef __attribute__((ext_vector_type(8))) short short8;
typedef __attribute__((ext_vector_type(4))) float f32x4;

__device__ __forceinline__ float bf2f(ushort u) {
  union { unsigned int i; float f; } v; v.i = ((unsigned int)u) << 16; return v.f;
}
__device__ __forceinline__ float bflo(unsigned int u) {
  union { unsigned int i; float f; } v; v.i = u << 16; return v.f;
}
__device__ __forceinline__ float bfhi(unsigned int u) {
  union { unsigned int i; float f; } v; v.i = u & 0xffff0000u; return v.f;
}
__device__ __forceinline__ ushort f2bf(float f) {
  union { float f; unsigned int i; } v; v.f = f;
  unsigned int x = v.i;
  return (ushort)((x + 0x7fffu + ((x >> 16) & 1u)) >> 16);  // RNE
}
// HW packed f32->bf16 (RNE); lo = S0, hi = S1 [guide T12 recipe, m214v22]
__device__ __forceinline__ unsigned int cvt_pk_bf16(float lo, float hi) {
  unsigned int r;
  asm("v_cvt_pk_bf16_f32 %0, %1, %2" : "=v"(r) : "v"(lo), "v"(hi));
  return r;
}

// ---------- prep: z<4 -> weight transpose [H][H] f32->bf16; z=4 -> rel cvt
__global__ __launch_bounds__(256) void prep_kernel(
    const float* __restrict__ s0, ushort* __restrict__ d0,
    const float* __restrict__ s1, ushort* __restrict__ d1,
    const float* __restrict__ s2, ushort* __restrict__ d2,
    const float* __restrict__ s3, ushort* __restrict__ d3,
    const float* __restrict__ rel, ushort* __restrict__ RelB) {
  if (blockIdx.z == 4) {
    int b = blockIdx.y * 24 + blockIdx.x;
    if (b < 96) {                                  // 96*1024 = NRELP*H
      int i = (b * 256 + threadIdx.x) * 4;         // 4-chunk stays within a row
      int row = i / H;
      ushort4 o = {0, 0, 0, 0};
      if (row < NREL) {
        float4 v = *(const float4*)(rel + i);
        o.x = f2bf(v.x); o.y = f2bf(v.y); o.z = f2bf(v.z); o.w = f2bf(v.w);
      }
      *(ushort4*)(RelB + i) = o;
    }
    return;
  }
  const float* src; ushort* dst;
  switch (blockIdx.z) {
    case 0:  src = s0; dst = d0; break;
    case 1:  src = s1; dst = d1; break;
    case 2:  src = s2; dst = d2; break;
    default: src = s3; dst = d3; break;
  }
  __shared__ float tile[32][33];
  int bx = blockIdx.x * 32, by = blockIdx.y * 32;
  int tx = threadIdx.x & 31, ty = threadIdx.x >> 5;  // ty 0..7
  #pragma unroll
  for (int i = 0; i < 32; i += 8)
    tile[ty + i][tx] = src[(size_t)(by + ty + i) * H + bx + tx];
  __syncthreads();
  #pragma unroll
  for (int i = 0; i < 32; i += 8)
    dst[(size_t)(bx + ty + i) * H + by + tx] = f2bf(tile[tx][ty + i]);
}

// ------------------------------------------------------------- bf16 MFMA GEMM
// C[M][N] = A[M][K] @ Bt[N][K]^T + bias. BK=64, XOR-swizzled LDS (T2 both-sides):
// physical 16B slot s of row r holds logical k-segment s^(r&7); ds_read applies
// the same involution. LDS is owned by the kernel and passed in (32 KB total).
__device__ __forceinline__ void gload_lds16(const void* g, void* l) {
  __builtin_amdgcn_global_load_lds(
      (const __attribute__((address_space(1))) unsigned int*)g,
      (__attribute__((address_space(3))) unsigned int*)l, 16, 0, 0);
}

#define BM 128
#define BN 128
#define BK 64

// shared epilogue + MFMA block
#define GEMM_COMPUTE_EPILOGUE()                                                \
  __syncthreads();                                                             \
  _Pragma("unroll")                                                            \
  for (int kk = 0; kk < 2; ++kk) {                                             \
    const int sw = (((kk << 2) | lk) ^ (lr & 7)) * 8;                          \
    short8 af[4], bfr[4];                                                      \
    _Pragma("unroll")                                                          \
    for (int m = 0; m < 4; ++m)                                                \
      af[m] = *(const short8*)(As + (wr * 64 + m * 16 + lr) * BK + sw);        \
    _Pragma("unroll")                                                          \
    for (int n = 0; n < 4; ++n)                                                \
      bfr[n] = *(const short8*)(Bs + (wc * 64 + n * 16 + lr) * BK + sw);       \
    _Pragma("unroll")                                                          \
    for (int m = 0; m < 4; ++m)                                                \
      _Pragma("unroll")                                                        \
      for (int n = 0; n < 4; ++n)                                              \
        acc[m][n] = __builtin_amdgcn_mfma_f32_16x16x32_bf16(af[m], bfr[n],     \
                                                            acc[m][n], 0, 0, 0);\
  }                                                                            \
  __syncthreads();

__device__ __forceinline__ void gemm_body(
    ushort* As, ushort* Bs,
    const ushort* __restrict__ A,    // [M][K] bf16
    const ushort* __restrict__ Bt,   // [N][K] bf16
    const float* __restrict__ bias,
    ushort* __restrict__ C,          // [M][N] bf16
    int M, int N, int K, int bx, int by) {
  const int tid = threadIdx.x;
  const int row0 = by * BM;
  const int col0 = bx * BN;
  const int wave = tid >> 6;
  const int lane = tid & 63;
  const int wr = wave >> 1, wc = wave & 1;
  const int lr = lane & 15, lk = lane >> 4;
  f32x4 acc[4][4];
  #pragma unroll
  for (int m = 0; m < 4; ++m)
    #pragma unroll
    for (int n = 0; n < 4; ++n) acc[m][n] = (f32x4)(0.f);

  for (int k0 = 0; k0 < K; k0 += BK) {
    #pragma unroll
    for (int i = 0; i < 4; ++i) {
      int c = tid + i * 256;
      int r = c >> 3, s = c & 7;
      int gs = s ^ (r & 7);
      gload_lds16(A  + (size_t)(row0 + r) * K + k0 + gs * 8, (char*)As + c * 16);
      gload_lds16(Bt + (size_t)(col0 + r) * K + k0 + gs * 8, (char*)Bs + c * 16);
    }
    GEMM_COMPUTE_EPILOGUE()
  }
  #pragma unroll
  for (int m = 0; m < 4; ++m) {
    #pragma unroll
    for (int n = 0; n < 4; ++n) {
      int col = col0 + wc * 64 + n * 16 + lr;
      float b = bias[col];
      #pragma unroll
      for (int j = 0; j < 4; ++j) {
        int row = row0 + wr * 64 + m * 16 + lk * 4 + j;
        C[(size_t)row * N + col] = f2bf(acc[m][n][j] + b);
      }
    }
  }
}

// A-side = f32 source, reg-staged + cvt_pk + ds_write (fused X->bf16 cvt)
__device__ __forceinline__ void gemm_body_a32(
    ushort* As, ushort* Bs,
    const float* __restrict__ A32,   // [M][K] f32
    const ushort* __restrict__ Bt,   // [N][K] bf16
    const float* __restrict__ bias,
    ushort* __restrict__ C,
    int M, int N, int K, int bx, int by) {
  const int tid = threadIdx.x;
  const int row0 = by * BM;
  const int col0 = bx * BN;
  const int wave = tid >> 6;
  const int lane = tid & 63;
  const int wr = wave >> 1, wc = wave & 1;
  const int lr = lane & 15, lk = lane >> 4;
  f32x4 acc[4][4];
  #pragma unroll
  for (int m = 0; m < 4; ++m)
    #pragma unroll
    for (int n = 0; n < 4; ++n) acc[m][n] = (f32x4)(0.f);

  for (int k0 = 0; k0 < K; k0 += BK) {
    #pragma unroll
    for (int i = 0; i < 4; ++i) {
      int c = tid + i * 256;
      int r = c >> 3, s = c & 7;
      int gs = s ^ (r & 7);
      // B: async to LDS
      gload_lds16(Bt + (size_t)(col0 + r) * K + k0 + gs * 8, (char*)Bs + c * 16);
      // A: f32 -> bf16 in-register, linear ds_write (conflict-free per wave)
      const float* src = A32 + (size_t)(row0 + r) * K + k0 + gs * 8;
      float4 f0 = *(const float4*)(src);
      float4 f1 = *(const float4*)(src + 4);
      uint4 w;
      w.x = cvt_pk_bf16(f0.x, f0.y);
      w.y = cvt_pk_bf16(f0.z, f0.w);
      w.z = cvt_pk_bf16(f1.x, f1.y);
      w.w = cvt_pk_bf16(f1.z, f1.w);
      *(uint4*)((char*)As + c * 16) = w;
    }
    GEMM_COMPUTE_EPILOGUE()
  }
  #pragma unroll
  for (int m = 0; m < 4; ++m) {
    #pragma unroll
    for (int n = 0; n < 4; ++n) {
      int col = col0 + wc * 64 + n * 16 + lr;
      float b = bias[col];
      #pragma unroll
      for (int j = 0; j < 4; ++j) {
        int row = row0 + wr * 64 + m * 16 + lk * 4 + j;
        C[(size_t)row * N + col] = f2bf(acc[m][n][j] + b);
      }
    }
  }
}

// ---- combined launch: blocks 0..11 = K/V-table GEMMs (hidden under Q-GEMM),
//      blocks 12..779 = Q = X(f32) @ WqT^T, XCD-swizzled (768 % 8 == 0)
__global__ __launch_bounds__(256, 2) void gemm_q_kv_kernel(
    const float* __restrict__ X, const ushort* __restrict__ WqT,
    const float* __restrict__ bq, ushort* __restrict__ Qbf,
    const ushort* __restrict__ RelB,
    const ushort* __restrict__ WkT, const float* __restrict__ bk, ushort* __restrict__ Ktab,
    const ushort* __restrict__ WvT, const float* __restrict__ bv, ushort* __restrict__ Vtab) {
  __shared__ ushort As[BM * BK];   // 16 KB
  __shared__ ushort Bs[BN * BK];   // 16 KB
  int lin = blockIdx.x;
  if (lin < 12) {
    if (lin < 6) gemm_body(As, Bs, RelB, WkT, bk, Ktab, NRELP, H, H, lin, 0);
    else         gemm_body(As, Bs, RelB, WvT, bv, Vtab, NRELP, H, H, lin - 6, 0);
    return;
  }
  int l2 = lin - 12;                       // 0..767
  int wg = (l2 & 7) * 96 + (l2 >> 3);      // bijective XCD swizzle
  gemm_body_a32(As, Bs, X, WqT, bq, Qbf, NTOK, H, H, wg % 6, wg / 6);
}

// big bf16 GEMM (OutProj): XCD-swizzled grid (6 x 128)
__global__ __launch_bounds__(256, 2) void gemm_bt_kernel(
    const ushort* __restrict__ A, const ushort* __restrict__ Bt,
    const float* __restrict__ bias, ushort* __restrict__ C,
    int M, int N, int K) {
  __shared__ ushort As[BM * BK];
  __shared__ ushort Bs[BN * BK];
  int lin = blockIdx.y * gridDim.x + blockIdx.x;
  int q = (gridDim.x * gridDim.y) >> 3;
  int wg = (lin & 7) * q + (lin >> 3);
  gemm_body(As, Bs, A, Bt, bias, C, M, N, K, wg % gridDim.x, wg / gridDim.x);
}

// ---------------------------------------------- gather-form GAT attention (v3)
// One lane per (token, head). K/V head-slices staged once per block in LDS
// (rows 0..99, stride 72 bf16). Zero cross-lane ops, one barrier.
__global__ __launch_bounds__(256) void attn3_kernel(
    const ushort* __restrict__ Q,     // [NTOK][H] bf16
    const ushort* __restrict__ Ktab,  // [NRELP][H] bf16
    const ushort* __restrict__ Vtab,  // [NRELP][H] bf16
    const int* __restrict__ graph,    // [NTOK][LL]
    const int* __restrict__ relid,    // [NTOK][LL]
    ushort* __restrict__ Ctx) {       // [NTOK][H] bf16
  __shared__ __align__(16) ushort Ks[NREL * PADW];  // 14.4 KB
  __shared__ __align__(16) ushort Vs[NREL * PADW];  // 14.4 KB
  const int tid = threadIdx.x;
  const int head = blockIdx.y;
  const int t = blockIdx.x * 256 + tid;

  #pragma unroll
  for (int i = 0; i < 4; ++i) {
    int c = tid + i * 256;
    if (c < NREL * 9) {
      int row = c / 9, slot = c - row * 9;
      int gs = (slot < 8) ? slot * 8 : 0;        // pad chunk: safe dup
      const size_t src = (size_t)row * H + head * DH + gs;
      gload_lds16(Ktab + src, (char*)Ks + (size_t)c * 16);
      gload_lds16(Vtab + src, (char*)Vs + (size_t)c * 16);
    }
  }

  const uint4* qp = (const uint4*)(Q + (size_t)t * H + head * DH);
  uint4 qw[8];
  #pragma unroll
  for (int j = 0; j < 8; ++j) qw[j] = qp[j];
  const int4* gp = (const int4*)(graph + (size_t)t * LL);
  const int4* rp = (const int4*)(relid + (size_t)t * LL);
  int4 ga = gp[0], gb = gp[1];
  int4 ra = rp[0], rb = rp[1];
  int gs[8] = {ga.x, ga.y, ga.z, ga.w, gb.x, gb.y, gb.z, gb.w};
  int rid[8] = {ra.x, ra.y, ra.z, ra.w, rb.x, rb.y, rb.z, rb.w};
  int koff[8];
  #pragma unroll
  for (int l = 0; l < 8; ++l) {
    int r = rid[l] < 0 ? 0 : rid[l];
    koff[l] = r * (PADW * 2);
  }

  __syncthreads();

  float s[8];
  #pragma unroll
  for (int l = 0; l < 8; ++l) s[l] = 0.f;
  #pragma unroll
  for (int j = 0; j < 8; ++j) {
    float qf[8];
    qf[0] = bflo(qw[j].x); qf[1] = bfhi(qw[j].x);
    qf[2] = bflo(qw[j].y); qf[3] = bfhi(qw[j].y);
    qf[4] = bflo(qw[j].z); qf[5] = bfhi(qw[j].z);
    qf[6] = bflo(qw[j].w); qf[7] = bfhi(qw[j].w);
    #pragma unroll
    for (int l = 0; l < 8; ++l) {
      uint4 kw = *(const uint4*)((const char*)Ks + koff[l] + j * 16);
      s[l] += qf[0] * bflo(kw.x) + qf[1] * bfhi(kw.x)
            + qf[2] * bflo(kw.y) + qf[3] * bfhi(kw.y)
            + qf[4] * bflo(kw.z) + qf[5] * bfhi(kw.z)
            + qf[6] * bflo(kw.w) + qf[7] * bfhi(kw.w);
    }
  }

  #pragma unroll
  for (int l = 0; l < 8; ++l)
    s[l] = (gs[l] != -1) ? s[l] * 0.125f : -10000.0f;
  float mx = s[0];
  #pragma unroll
  for (int l = 1; l < 8; ++l) mx = fmaxf(mx, s[l]);
  float p[8], den = 0.f;
  #pragma unroll
  for (int l = 0; l < 8; ++l) { p[l] = __expf(s[l] - mx); den += p[l]; }
  float inv = 1.f / den;
  #pragma unroll
  for (int l = 0; l < 8; ++l) p[l] *= inv;

  ushort* cp = Ctx + (size_t)t * H + head * DH;
  #pragma unroll
  for (int j = 0; j < 8; ++j) {
    float a[8];
    #pragma unroll
    for (int d = 0; d < 8; ++d) a[d] = 0.f;
    #pragma unroll
    for (int l = 0; l < 8; ++l) {
      uint4 vw = *(const uint4*)((const char*)Vs + koff[l] + j * 16);
      a[0] += p[l] * bflo(vw.x); a[1] += p[l] * bfhi(vw.x);
      a[2] += p[l] * bflo(vw.y); a[3] += p[l] * bfhi(vw.y);
      a[4] += p[l] * bflo(vw.z); a[5] += p[l] * bfhi(vw.z);
      a[6] += p[l] * bflo(vw.w); a[7] += p[l] * bfhi(vw.w);
    }
    short8 o;
    #pragma unroll
    for (int d = 0; d < 8; ++d) o[d] = (short)f2bf(a[d]);
    *(short8*)(cp + j * 8) = o;
  }
}

// ------------------------------------- residual + LayerNorm (192 thr, float4)
__global__ __launch_bounds__(192) void ln_kernel(
    const float* __restrict__ text, const ushort* __restrict__ op,
    const float* __restrict__ gamma, const float* __restrict__ beta,
    float* __restrict__ out) {
  int t = blockIdx.x;
  int c0 = threadIdx.x * 4;
  float4 tv = *(const float4*)(text + (size_t)t * H + c0);
  ushort4 ov = *(const ushort4*)(op + (size_t)t * H + c0);
  float x0 = tv.x + bf2f(ov.x), x1 = tv.y + bf2f(ov.y);
  float x2 = tv.z + bf2f(ov.z), x3 = tv.w + bf2f(ov.w);
  float s = x0 + x1 + x2 + x3;
  float s2 = x0 * x0 + x1 * x1 + x2 * x2 + x3 * x3;
  #pragma unroll
  for (int off = 32; off > 0; off >>= 1) {
    s  += __shfl_xor(s, off, 64);
    s2 += __shfl_xor(s2, off, 64);
  }
  __shared__ float red[2][3];
  int wave = threadIdx.x >> 6, lane = threadIdx.x & 63;
  if (lane == 0) { red[0][wave] = s; red[1][wave] = s2; }
  __syncthreads();
  s  = red[0][0] + red[0][1] + red[0][2];
  s2 = red[1][0] + red[1][1] + red[1][2];
  float mu = s * (1.f / H);
  float var = s2 * (1.f / H) - mu * mu;
  float rs = rsqrtf(var + 1e-5f);
  float4 g4 = *(const float4*)(gamma + c0);
  float4 b4 = *(const float4*)(beta + c0);
  float4 o4;
  o4.x = (x0 - mu) * rs * g4.x + b4.x;
  o4.y = (x1 - mu) * rs * g4.y + b4.y;
  o4.z = (x2 - mu) * rs * g4.z + b4.z;
  o4.w = (x3 - mu) * rs * g4.w + b4.w;
  *(float4*)(out + (size_t)t * H + c0) = o4;
}

// ---------------------------------------------------------------------- driver
extern "C" void kernel_launch(void* const* d_in, const int* in_sizes, int n_in,
                              void* d_out, int out_size, void* d_ws, size_t ws_size,
                              hipStream_t stream) {
  const float* text      = (const float*)d_in[0];
  const int*   graph     = (const int*)d_in[1];
  const int*   relid     = (const int*)d_in[2];
  const float* rel_table = (const float*)d_in[3];
  const float* Wq = (const float*)d_in[4];  const float* bq = (const float*)d_in[5];
  const float* Wk = (const float*)d_in[6];  const float* bk = (const float*)d_in[7];
  const float* Wv = (const float*)d_in[8];  const float* bv = (const float*)d_in[9];
  const float* Wo = (const float*)d_in[10]; const float* bo = (const float*)d_in[11];
  const float* gamma = (const float*)d_in[12];
  const float* beta  = (const float*)d_in[13];
  float* out = (float*)d_out;
  char* ws = (char*)d_ws;

  const size_t TOKH = (size_t)NTOK * H;           // 12,582,912
  size_t off = 0;
  ushort* Ctx  = (ushort*)(ws + off); off += TOKH * 2;             // attn out
  ushort* Qbf  = (ushort*)(ws + off); off += TOKH * 2;             // Q, reused as OutProj
  ushort* WqT  = (ushort*)(ws + off); off += (size_t)H * H * 2;
  ushort* WoT  = (ushort*)(ws + off); off += (size_t)H * H * 2;
  ushort* WkT  = (ushort*)(ws + off); off += (size_t)H * H * 2;
  ushort* WvT  = (ushort*)(ws + off); off += (size_t)H * H * 2;
  ushort* RelB = (ushort*)(ws + off); off += (size_t)NRELP * H * 2;
  ushort* Ktab = (ushort*)(ws + off); off += (size_t)NRELP * H * 2;
  ushort* Vtab = (ushort*)(ws + off); off += (size_t)NRELP * H * 2;

  // 1) weight transposes + rel_table cvt (one launch)
  prep_kernel<<<dim3(24, 24, 5), 256, 0, stream>>>(
      Wq, WqT, Wo, WoT, Wk, WkT, Wv, WvT, rel_table, RelB);
  // 2) Q = X(f32) @ WqT^T + bq  (fused cvt), with K/V-table GEMMs hidden inside
  gemm_q_kv_kernel<<<780, 256, 0, stream>>>(
      text, WqT, bq, Qbf, RelB, WkT, bk, Ktab, WvT, bv, Vtab);
  // 3) attention -> Ctx
  dim3 ga(NTOK / 256, NH);
  attn3_kernel<<<ga, 256, 0, stream>>>(Qbf, Ktab, Vtab, graph, relid, Ctx);
  // 4) OutProj = Ctx @ WoT^T + bo (reuse Qbf storage)
  dim3 g1(H / BN, NTOK / BM);
  gemm_bt_kernel<<<g1, 256, 0, stream>>>(Ctx, WoT, bo, Qbf, NTOK, H, H);
  // 5) residual + LayerNorm -> out
  ln_kernel<<<NTOK, 192, 0, stream>>>(text, Qbf, gamma, beta, out);
}